// Round 18
// baseline (44.342 us; speedup 1.0000x reference)
//
#include <hip/hip_runtime.h>
#include <hip/hip_bf16.h>
#include <math.h>

#define B 16
#define T 512
#define D 256
#define H 4
#define HD 64
#define MAXREL 30
#define NREL 61
#define M_ROWS (B*T)     // 8192
#define QBLK 128

typedef __attribute__((ext_vector_type(8))) short bf16x8;
typedef __attribute__((ext_vector_type(4))) float f32x4;
typedef unsigned short ush;

__device__ inline ush f2b(float f) {
    __hip_bfloat16 h = __float2bfloat16(f);
    union { __hip_bfloat16 h; ush u; } c; c.h = h; return c.u;
}
__device__ inline float b2f(ush u) {
    union { ush u; __hip_bfloat16 h; } c; c.u = u; return __bfloat162float(c.h);
}
// pack two floats -> bf16 pair (low = a, high = b); lowers to v_cvt_pk_bf16_f32
__device__ inline unsigned int pk2(float a, float b) {
    __hip_bfloat162 h = __float22bfloat162_rn(make_float2(a, b));
    union { __hip_bfloat162 h; unsigned int u; } c; c.h = h; return c.u;
}
// swizzled byte offset inside a [rows][64] bf16 tile (128B rows)
__device__ inline int swz(int row, int byteoff) {
    return row * 128 + (byteoff ^ ((row & 7) << 4));
}
// swizzled byte offset inside a [rows][128] bf16 tile (256B rows)
__device__ inline int swz256(int row, int byteoff) {
    return row * 256 + (byteoff ^ ((row & 7) << 4));
}
// swizzled byte offset inside a [rows][256] bf16 tile (512B rows)
__device__ inline int swz512(int row, int byteoff) {
    return row * 512 + (byteoff ^ ((row & 7) << 4));
}
// fp32 -> bf16x8 conversion of 8 consecutive floats
__device__ inline bf16x8 cvt8(const float* p) {
    float4 a = *(const float4*)p, b = *(const float4*)(p + 4);
    bf16x8 o;
    o[0] = (short)f2b(a.x); o[1] = (short)f2b(a.y);
    o[2] = (short)f2b(a.z); o[3] = (short)f2b(a.w);
    o[4] = (short)f2b(b.x); o[5] = (short)f2b(b.y);
    o[6] = (short)f2b(b.z); o[7] = (short)f2b(b.w);
    return o;
}

#define SCL 0.1803368801111204f   // 0.125 * log2(e)

// ---------------------------------------------------------------------------
// LayerNorm only: 512 blocks x 16 rows -> xb bf16.
// ---------------------------------------------------------------------------
__global__ __launch_bounds__(256) void ln_kernel(const float* __restrict__ x,
                                                 const float* __restrict__ gamma,
                                                 const float* __restrict__ beta,
                                                 ush* __restrict__ xb) {
    int bid = blockIdx.x;
    int tid = threadIdx.x;
    int lane = tid & 63;
    float4 g = *(const float4*)(gamma + lane * 4);
    float4 bb = *(const float4*)(beta + lane * 4);
    #pragma unroll
    for (int it = 0; it < 4; ++it) {
        int row = bid * 16 + it * 4 + (tid >> 6);
        const float* xr = x + (size_t)row * D;
        float4 v = *(const float4*)(xr + lane * 4);
        float s = v.x + v.y + v.z + v.w;
        #pragma unroll
        for (int off = 32; off; off >>= 1) s += __shfl_xor(s, off);
        float mu = s * (1.f / 256.f);
        float dx = v.x - mu, dy = v.y - mu, dz = v.z - mu, dw = v.w - mu;
        float vs = dx*dx + dy*dy + dz*dz + dw*dw;
        #pragma unroll
        for (int off = 32; off; off >>= 1) vs += __shfl_xor(vs, off);
        float rstd = rsqrtf(vs * (1.f / 256.f) + 1e-5f);
        ushort4 o;
        o.x = f2b(dx * rstd * g.x + bb.x);
        o.y = f2b(dy * rstd * g.y + bb.y);
        o.z = f2b(dz * rstd * g.z + bb.z);
        o.w = f2b(dw * rstd * g.w + bb.w);
        *(ushort4*)(xb + (size_t)row * D + lane * 4) = o;
    }
}

// ---------------------------------------------------------------------------
// Fused QKV projection + pos table. grid (64, 4, 4):
//  z<3 : 128(tok)x64(feat) tile, BK=128, W staged from fp32 inline. 48KB LDS.
//  z==3: x==0 -> MFMA pos table for head y -> pospb[h][rel][d] bf16 (A_s reused).
// ---------------------------------------------------------------------------
__global__ __launch_bounds__(256, 3) void qkv_mfma(const ush* __restrict__ A,
                                                   const float* __restrict__ Wq,
                                                   const float* __restrict__ Wk,
                                                   const float* __restrict__ Wv,
                                                   const float* __restrict__ bq,
                                                   const float* __restrict__ bk,
                                                   const float* __restrict__ bv,
                                                   const float* __restrict__ Wpos,
                                                   const float* __restrict__ bpos,
                                                   ush* __restrict__ pospb,
                                                   ush* __restrict__ qb,
                                                   ush* __restrict__ kbuf,
                                                   ush* __restrict__ vtb) {
    __shared__ __attribute__((aligned(16))) ush A_s[128 * 128];  // token tile / pos wpS
    __shared__ __attribute__((aligned(16))) ush B_s[64 * 128];   // W tile
    int tid = threadIdx.x;
    int w = tid >> 6, l = tid & 63;
    int lg = l >> 4, ln = l & 15;

    if (blockIdx.z == 3) {
        // ---- MFMA pos table for head h (x==0 blocks only) ----
        if (blockIdx.x != 0) return;
        ush* wpS = A_s;              // [64][256] swizzled, 32KB
        int h = blockIdx.y;
        const float* wsrc = Wpos + (size_t)(h * 64) * D;
        #pragma unroll
        for (int c = 0; c < 16; ++c) {
            int idx = c * 256 + tid;
            int row = idx >> 6, col = (idx & 63) * 4;
            float4 v = *(const float4*)(wsrc + (size_t)row * D + col);
            ushort4 o; o.x = f2b(v.x); o.y = f2b(v.y); o.z = f2b(v.z); o.w = f2b(v.w);
            *(ushort4*)((char*)wpS + swz512(row, col * 2)) = o;
        }
        int p = w * 16 + ln;
        bf16x8 af[8];
        #pragma unroll
        for (int ks = 0; ks < 8; ++ks) {
            #pragma unroll
            for (int j = 0; j < 8; ++j) {
                int k = ks * 32 + lg * 8 + j;
                int i = k >> 1;
                float dt = __expf(-(2.f * i) * (9.210340371976184f / 256.f));
                float ang = (float)p * dt;
                float v = (k & 1) ? __cosf(ang) : __sinf(ang);
                af[ks][j] = (short)f2b(v);
            }
        }
        __syncthreads();
        f32x4 acc[4] = {};
        #pragma unroll
        for (int ks = 0; ks < 8; ++ks) {
            int kbyte = (ks * 32 + lg * 8) * 2;
            #pragma unroll
            for (int ct = 0; ct < 4; ++ct) {
                bf16x8 bf = *(const bf16x8*)((const char*)wpS + swz512(ct * 16 + ln, kbyte));
                acc[ct] = __builtin_amdgcn_mfma_f32_16x16x32_bf16(af[ks], bf, acc[ct], 0, 0, 0);
            }
        }
        #pragma unroll
        for (int ct = 0; ct < 4; ++ct) {
            int dcol = ct * 16 + ln;
            float bb = bpos[h * 64 + dcol];
            #pragma unroll
            for (int r = 0; r < 4; ++r) {
                int pr = w * 16 + lg * 4 + r;
                pospb[(size_t)h * 4096 + pr * 64 + dcol] = f2b(acc[ct][r] + bb);
            }
        }
        return;
    }

    int wr = w >> 1, wc = w & 1;
    int i0 = blockIdx.x * 128;   // tokens
    int j0 = blockIdx.y * 64;    // features
    int z = blockIdx.z;
    const float* Wsel = z == 0 ? Wq : (z == 1 ? Wk : Wv);
    const float* Wp = Wsel + (size_t)j0 * D;
    const ush* Ap = A + (size_t)i0 * D;
    const float* bias = z == 0 ? bq : (z == 1 ? bk : bv);
    f32x4 acc[2][4] = {};

    #pragma unroll 1
    for (int kb2 = 0; kb2 < 2; ++kb2) {
        int k0 = kb2 * 128;
        if (kb2) __syncthreads();
        #pragma unroll
        for (int c = 0; c < 8; ++c) {
            int u = c * 256 + tid;
            int row = u >> 4, sub = u & 15;
            *(bf16x8*)((char*)A_s + swz256(row, sub * 16)) = *(const bf16x8*)(Ap + (size_t)row * D + k0 + sub * 8);
        }
        #pragma unroll
        for (int c = 0; c < 4; ++c) {
            int u = c * 256 + tid;
            int row = u >> 4, sub = u & 15;
            *(bf16x8*)((char*)B_s + swz256(row, sub * 16)) = cvt8(Wp + (size_t)row * D + k0 + sub * 8);
        }
        __syncthreads();
        __builtin_amdgcn_s_setprio(1);
        #pragma unroll
        for (int ksub = 0; ksub < 4; ++ksub) {
            int kbyte = ksub * 64 + lg * 16;
            bf16x8 af[2], bfr[4];
            #pragma unroll
            for (int mi = 0; mi < 2; ++mi)
                af[mi] = *(const bf16x8*)((const char*)B_s + swz256(wr * 32 + mi * 16 + ln, kbyte));
            #pragma unroll
            for (int ni = 0; ni < 4; ++ni)
                bfr[ni] = *(const bf16x8*)((const char*)A_s + swz256(wc * 64 + ni * 16 + ln, kbyte));
            #pragma unroll
            for (int mi = 0; mi < 2; ++mi)
                #pragma unroll
                for (int ni = 0; ni < 4; ++ni)
                    acc[mi][ni] = __builtin_amdgcn_mfma_f32_16x16x32_bf16(af[mi], bfr[ni], acc[mi][ni], 0, 0, 0);
        }
        __builtin_amdgcn_s_setprio(0);
    }

    if (z == 2) {
        // V^T: D[j][t], 4 consecutive j per quad -> scalar stores vtb[j][t]
        #pragma unroll
        for (int mi = 0; mi < 2; ++mi) {
            int jb = j0 + wr * 32 + mi * 16 + lg * 4;
            float4 bv4 = *(const float4*)(bias + jb);
            float bvv[4] = {bv4.x, bv4.y, bv4.z, bv4.w};
            #pragma unroll
            for (int ni = 0; ni < 4; ++ni) {
                int t = i0 + wc * 64 + ni * 16 + ln;
                #pragma unroll
                for (int r = 0; r < 4; ++r)
                    vtb[(size_t)(jb + r) * M_ROWS + t] = f2b(acc[mi][ni][r] + bvv[r]);
            }
        }
    } else {
        ush* ob = (z == 0) ? qb : kbuf;
        #pragma unroll
        for (int mi = 0; mi < 2; ++mi) {
            int jb = j0 + wr * 32 + mi * 16 + lg * 4;
            float4 bv4 = *(const float4*)(bias + jb);
            #pragma unroll
            for (int ni = 0; ni < 4; ++ni) {
                int t = i0 + wc * 64 + ni * 16 + ln;
                ushort4 o;
                o.x = f2b(acc[mi][ni][0] + bv4.x); o.y = f2b(acc[mi][ni][1] + bv4.y);
                o.z = f2b(acc[mi][ni][2] + bv4.z); o.w = f2b(acc[mi][ni][3] + bv4.w);
                *(ushort4*)(ob + (size_t)t * D + jb) = o;
            }
        }
    }
}

// ---------------------------------------------------------------------------
// Out-projection: 64x64 tiles, grid (128, 4) = 512 blocks = 2/CU exact.
// Wo staged from fp32 inline.
// ---------------------------------------------------------------------------
__global__ __launch_bounds__(256, 2) void outproj_mfma(const ush* __restrict__ A,
                                                       const float* __restrict__ W,
                                                       const float* __restrict__ bias,
                                                       float* __restrict__ of) {
    __shared__ __attribute__((aligned(16))) ush A_s[64 * 128];
    __shared__ __attribute__((aligned(16))) ush B_s[64 * 128];
    int tid = threadIdx.x;
    int w = tid >> 6, l = tid & 63;
    int lg = l >> 4, ln = l & 15;
    int wr = w >> 1, wc = w & 1;
    int i0 = blockIdx.x * 64;   // tokens
    int j0 = blockIdx.y * 64;   // features
    const ush* Ap = A + (size_t)i0 * D;
    const float* Wp = W + (size_t)j0 * D;
    f32x4 acc[2][2] = {};

    #pragma unroll 1
    for (int kb2 = 0; kb2 < 2; ++kb2) {
        int k0 = kb2 * 128;
        if (kb2) __syncthreads();
        #pragma unroll
        for (int c = 0; c < 4; ++c) {
            int u = c * 256 + tid;
            int row = u >> 4, sub = u & 15;
            *(bf16x8*)((char*)A_s + swz256(row, sub * 16)) = *(const bf16x8*)(Ap + (size_t)row * D + k0 + sub * 8);
            *(bf16x8*)((char*)B_s + swz256(row, sub * 16)) = cvt8(Wp + (size_t)row * D + k0 + sub * 8);
        }
        __syncthreads();
        __builtin_amdgcn_s_setprio(1);
        #pragma unroll
        for (int ksub = 0; ksub < 4; ++ksub) {
            int kbyte = ksub * 64 + lg * 16;
            bf16x8 af[2], bfr[2];
            #pragma unroll
            for (int mi = 0; mi < 2; ++mi)
                af[mi] = *(const bf16x8*)((const char*)B_s + swz256(wr * 32 + mi * 16 + ln, kbyte));
            #pragma unroll
            for (int ni = 0; ni < 2; ++ni)
                bfr[ni] = *(const bf16x8*)((const char*)A_s + swz256(wc * 32 + ni * 16 + ln, kbyte));
            #pragma unroll
            for (int mi = 0; mi < 2; ++mi)
                #pragma unroll
                for (int ni = 0; ni < 2; ++ni)
                    acc[mi][ni] = __builtin_amdgcn_mfma_f32_16x16x32_bf16(af[mi], bfr[ni], acc[mi][ni], 0, 0, 0);
        }
        __builtin_amdgcn_s_setprio(0);
    }

    #pragma unroll
    for (int mi = 0; mi < 2; ++mi) {
        int jb = j0 + wr * 32 + mi * 16 + lg * 4;
        float4 bv4 = *(const float4*)(bias + jb);
        #pragma unroll
        for (int ni = 0; ni < 2; ++ni) {
            int t = i0 + wc * 32 + ni * 16 + ln;
            float4 o;
            o.x = acc[mi][ni][0] + bv4.x; o.y = acc[mi][ni][1] + bv4.y;
            o.z = acc[mi][ni][2] + bv4.z; o.w = acc[mi][ni][3] + bv4.w;
            *(float4*)(of + (size_t)t * D + jb) = o;
        }
    }
}

// ---------------------------------------------------------------------------
// Flash MFMA attention (R16 verbatim): TWO-TILE software pipeline, 4 K/V LDS
// buffers, 2 KV tiles per barrier. QBLK=128, 8 waves, swapped QK^T, cvt_pk P
// writes, static-max exp2 softmax, l-sum via ones-MFMA.
// ---------------------------------------------------------------------------
__global__ __launch_bounds__(512, 2) void attn_mfma(const ush* __restrict__ qb,
                                                    const ush* __restrict__ kb,
                                                    const ush* __restrict__ vtb,
                                                    const ush* __restrict__ pospb,
                                                    const float* __restrict__ u_bias,
                                                    const float* __restrict__ v_bias,
                                                    ush* __restrict__ ctxb) {
    __shared__ __attribute__((aligned(16))) ush Kd[4][64 * 64];   // 32KB: 2 ping-pong pairs (buf2 = posp in prologue)
    __shared__ __attribute__((aligned(16))) ush Vd[4][64 * 64];   // 32KB
    __shared__ __attribute__((aligned(16))) ush pdS[8][16 * 66];  // per-wave pd[q_loc][rel]
    __shared__ __attribute__((aligned(16))) ush PlS[8][16 * 64];  // per-wave P[q_loc][s] (swizzled)

    int tid = threadIdx.x;
    int w = tid >> 6;          // wave 0..7
    int l = tid & 63;
    int lg = l >> 4, ln = l & 15;
    int bh = blockIdx.x;
    int b = bh >> 2, h = bh & 3;
    int t0 = blockIdx.y * QBLK;
    const size_t baseBH = ((size_t)b * T) * D + h * HD;

    // ---- Q fragments in registers, pre-scaled by 0.125*log2(e) ----
    bf16x8 qu[2], qv[2];
    {
        const ush* qrow = qb + baseBH + (size_t)(t0 + w * 16 + ln) * D;
        int c0 = lg * 8;
        #pragma unroll
        for (int ks = 0; ks < 2; ++ks) {
            bf16x8 ld = *(const bf16x8*)(qrow + ks * 32 + c0);
            float4 ub0 = *(const float4*)(u_bias + h * HD + ks * 32 + c0);
            float4 ub1 = *(const float4*)(u_bias + h * HD + ks * 32 + c0 + 4);
            float4 vb0 = *(const float4*)(v_bias + h * HD + ks * 32 + c0);
            float4 vb1 = *(const float4*)(v_bias + h * HD + ks * 32 + c0 + 4);
            float ubv[8] = {ub0.x,ub0.y,ub0.z,ub0.w,ub1.x,ub1.y,ub1.z,ub1.w};
            float vbv[8] = {vb0.x,vb0.y,vb0.z,vb0.w,vb1.x,vb1.y,vb1.z,vb1.w};
            #pragma unroll
            for (int j = 0; j < 8; ++j) {
                float f = b2f((ush)ld[j]);
                qu[ks][j] = (short)f2b((f + ubv[j]) * SCL);
                qv[ks][j] = (short)f2b((f + vbv[j]) * SCL);
            }
        }
    }

    // staging chunk index: each of 512 threads owns ONE 16B chunk of a 64x64 tile
    int r0 = tid >> 3, c0 = tid & 7;
    const ush* kbase = kb + baseBH;
    const ush* vbase = vtb + (size_t)(h * HD) * M_ROWS + (size_t)b * T;
    const ush* pbase = pospb + (size_t)h * 4096;

    // ---- prologue: stage posp->Kd[2], tiles 0,1 -> pair {0,1}; prefetch 2,3 ----
    {
        bf16x8 pp0 = *(const bf16x8*)(pbase + r0 * 64 + c0 * 8);
        bf16x8 k0 = *(const bf16x8*)(kbase + (size_t)r0 * D + c0 * 8);
        bf16x8 k1 = *(const bf16x8*)(kbase + (size_t)(64 + r0) * D + c0 * 8);
        bf16x8 v0 = *(const bf16x8*)(vbase + (size_t)r0 * M_ROWS + c0 * 8);
        bf16x8 v1 = *(const bf16x8*)(vbase + (size_t)r0 * M_ROWS + 64 + c0 * 8);
        *(bf16x8*)((char*)Kd[2] + swz(r0, c0 * 16)) = pp0;
        *(bf16x8*)((char*)Kd[0] + swz(r0, c0 * 16)) = k0;
        *(bf16x8*)((char*)Kd[1] + swz(r0, c0 * 16)) = k1;
        *(bf16x8*)((char*)Vd[0] + swz(r0, c0 * 16)) = v0;
        *(bf16x8*)((char*)Vd[1] + swz(r0, c0 * 16)) = v1;
    }
    bf16x8 sk0 = *(const bf16x8*)(kbase + (size_t)(128 + r0) * D + c0 * 8);
    bf16x8 sk1 = *(const bf16x8*)(kbase + (size_t)(192 + r0) * D + c0 * 8);
    bf16x8 sv0 = *(const bf16x8*)(vbase + (size_t)r0 * M_ROWS + 128 + c0 * 8);
    bf16x8 sv1 = *(const bf16x8*)(vbase + (size_t)r0 * M_ROWS + 192 + c0 * 8);
    __syncthreads();

    // ---- pd[q_loc][rel] via MFMA from Kd[2] (posp), log2-scaled via qv ----
    ush* pdW = pdS[w];
    {
        f32x4 pacc[4] = {};
        #pragma unroll
        for (int ks = 0; ks < 2; ++ks)
            #pragma unroll
            for (int ct = 0; ct < 4; ++ct) {
                bf16x8 bf = *(const bf16x8*)((const char*)Kd[2] + swz(ct * 16 + ln, (ks * 32 + lg * 8) * 2));
                pacc[ct] = __builtin_amdgcn_mfma_f32_16x16x32_bf16(qv[ks], bf, pacc[ct], 0, 0, 0);
            }
        // cols 61..63 pad, never gathered (|rel|<=30)
        #pragma unroll
        for (int ct = 0; ct < 4; ++ct)
            #pragma unroll
            for (int r = 0; r < 4; ++r)
                pdW[(lg * 4 + r) * 66 + ct * 16 + ln] = f2b(pacc[ct][r]);
    }
    // per-lane scalar constants for fully-clipped tiles (lane's q_loc = ln)
    float pdlo = b2f(pdW[ln * 66 + 0]);
    float pdhi = b2f(pdW[ln * 66 + 60]);
    __syncthreads();   // all waves done reading Kd[2] before iter0 commit targets it

    // ---- main loop: 4 iterations, 2 KV tiles per barrier ----
    f32x4 lacc = {};
    f32x4 o_acc[4] = {};
    ush* pw = PlS[w];
    bf16x8 ones;
    #pragma unroll
    for (int j = 0; j < 8; ++j) ones[j] = (short)0x3F80;   // bf16 1.0

    #pragma unroll 1
    for (int it = 0; it < 4; ++it) {
        int cb = (it & 1) * 2;   // current pair base {cb, cb+1}
        int ob = cb ^ 2;         // other pair base (commit target)
        // commit tiles 2it+2, 2it+3 (readers of pair ob finished before last barrier)
        if (it < 3) {
            *(bf16x8*)((char*)Kd[ob] + swz(r0, c0 * 16)) = sk0;
            *(bf16x8*)((char*)Kd[ob + 1] + swz(r0, c0 * 16)) = sk1;
            *(bf16x8*)((char*)Vd[ob] + swz(r0, c0 * 16)) = sv0;
            *(bf16x8*)((char*)Vd[ob + 1] + swz(r0, c0 * 16)) = sv1;
        }
        // issue loads for tiles 2it+4, 2it+5
        if (it < 2) {
            int sn = it * 128 + 256;
            sk0 = *(const bf16x8*)(kbase + (size_t)(sn + r0) * D + c0 * 8);
            sk1 = *(const bf16x8*)(kbase + (size_t)(sn + 64 + r0) * D + c0 * 8);
            sv0 = *(const bf16x8*)(vbase + (size_t)r0 * M_ROWS + sn + c0 * 8);
            sv1 = *(const bf16x8*)(vbase + (size_t)r0 * M_ROWS + sn + 64 + c0 * 8);
        }

        // ---- two tiles back-to-back (tt=1's QK^T independent of tt=0's PV) ----
        #pragma unroll
        for (int tt = 0; tt < 2; ++tt) {
            int s0 = (2 * it + tt) * 64;
            const char* Kc = (const char*)Kd[cb + tt];
            const char* Vc = (const char*)Vd[cb + tt];

            // sacc init: per-lane scalar pd for fully-clipped tiles
            // all rel >= 30 <=> dlt >= 192; all rel <= -30 <=> dlt <= -128
            int dlt = s0 - t0;
            float cinit;
            if (dlt >= 192) cinit = pdhi;
            else if (dlt <= -128) cinit = pdlo;
            else cinit = 0.f;
            f32x4 sacc[4];
            #pragma unroll
            for (int ct = 0; ct < 4; ++ct)
                #pragma unroll
                for (int r = 0; r < 4; ++r) sacc[ct][r] = cinit;

            // SWAPPED QK^T: D = S^T, lane holds s = ct*16 + lg*4 + r, q = w*16 + ln
            __builtin_amdgcn_s_setprio(1);
            #pragma unroll
            for (int ks = 0; ks < 2; ++ks)
                #pragma unroll
                for (int ct = 0; ct < 4; ++ct) {
                    bf16x8 kf = *(const bf16x8*)(Kc + swz(ct * 16 + ln, (ks * 32 + lg * 8) * 2));
                    sacc[ct] = __builtin_amdgcn_mfma_f32_16x16x32_bf16(kf, qu[ks], sacc[ct], 0, 0, 0);
                }
            __builtin_amdgcn_s_setprio(0);

            // partially-clipped tiles: gather pd from LDS (q_loc = ln per lane)
            if (dlt > -128 && dlt < 192) {
                int t_glob = t0 + w * 16 + ln;
                #pragma unroll
                for (int ct = 0; ct < 4; ++ct) {
                    #pragma unroll
                    for (int r = 0; r < 4; ++r) {
                        int s_g = s0 + ct * 16 + lg * 4 + r;
                        int rel = s_g - t_glob;
                        rel = rel < -MAXREL ? -MAXREL : (rel > MAXREL ? MAXREL : rel);
                        sacc[ct][r] += b2f(pdW[ln * 66 + rel + MAXREL]);
                    }
                }
            }

            // static-max softmax: P = exp2(s) directly
            #pragma unroll
            for (int ct = 0; ct < 4; ++ct)
                #pragma unroll
                for (int r = 0; r < 4; ++r)
                    sacc[ct][r] = exp2f(sacc[ct][r]);

            // P -> per-wave LDS, packed pairs (s-adjacent): 8 x b32 writes
            #pragma unroll
            for (int ct = 0; ct < 4; ++ct)
                #pragma unroll
                for (int rr = 0; rr < 2; ++rr)
                    *(unsigned int*)((char*)pw + swz(ln, (ct * 16 + lg * 4 + rr * 2) * 2)) =
                        pk2(sacc[ct][rr * 2], sacc[ct][rr * 2 + 1]);

            // PV + l-sum via ones-MFMA (A-frag reads P[q=ln][s-chunk])
            __builtin_amdgcn_s_setprio(1);
            #pragma unroll
            for (int ks = 0; ks < 2; ++ks) {
                bf16x8 pa = *(const bf16x8*)((const char*)pw + swz(ln, (ks * 32 + lg * 8) * 2));
                #pragma unroll
                for (int cd = 0; cd < 4; ++cd) {
                    bf16x8 bv8 = *(const bf16x8*)(Vc + swz(cd * 16 + ln, (ks * 32 + lg * 8) * 2));
                    o_acc[cd] = __builtin_amdgcn_mfma_f32_16x16x32_bf16(pa, bv8, o_acc[cd], 0, 0, 0);
                }
                lacc = __builtin_amdgcn_mfma_f32_16x16x32_bf16(pa, ones, lacc, 0, 0, 0);
            }
            __builtin_amdgcn_s_setprio(0);
        }

        __syncthreads();   // single barrier per 2 tiles
    }

    // ---- normalize + write ctx (bf16 row-major) ----
    float inv[4];
    #pragma unroll
    for (int r = 0; r < 4; ++r) inv[r] = 1.f / lacc[r];
    #pragma unroll
    for (int cd = 0; cd < 4; ++cd)
        #pragma unroll
        for (int r = 0; r < 4; ++r) {
            int t_loc = w * 16 + lg * 4 + r;
            ctxb[baseBH + (size_t)(t0 + t_loc) * D + cd * 16 + ln] = f2b(o_acc[cd][r] * inv[r]);
        }
}

// ---------------------------------------------------------------------------
extern "C" void kernel_launch(void* const* d_in, const int* in_sizes, int n_in,
                              void* d_out, int out_size, void* d_ws, size_t ws_size,
                              hipStream_t stream) {
    const float* inputs  = (const float*)d_in[0];
    const float* ln_g    = (const float*)d_in[1];
    const float* ln_b    = (const float*)d_in[2];
    const float* Wq      = (const float*)d_in[3];
    const float* bq      = (const float*)d_in[4];
    const float* Wk      = (const float*)d_in[5];
    const float* bk      = (const float*)d_in[6];
    const float* Wv      = (const float*)d_in[7];
    const float* bv      = (const float*)d_in[8];
    const float* Wpos    = (const float*)d_in[9];
    const float* bpos    = (const float*)d_in[10];
    const float* Wo      = (const float*)d_in[11];
    const float* bo      = (const float*)d_in[12];
    const float* u_bias  = (const float*)d_in[13];
    const float* v_bias  = (const float*)d_in[14];
    float* out = (float*)d_out;

    char* w = (char*)d_ws;
    ush* xb    = (ush*)w;  w += (size_t)M_ROWS * D * 2;   // 4MB
    ush* qb    = (ush*)w;  w += (size_t)M_ROWS * D * 2;
    ush* kbuf  = (ush*)w;  w += (size_t)M_ROWS * D * 2;
    ush* vtb   = (ush*)w;  w += (size_t)M_ROWS * D * 2;
    ush* ctxb  = (ush*)w;  w += (size_t)M_ROWS * D * 2;
    ush* pospb = (ush*)w;  w += (size_t)4 * 64 * 64 * 2;  // 32KB

    ln_kernel<<<512, 256, 0, stream>>>(inputs, ln_g, ln_b, xb);

    qkv_mfma<<<dim3(M_ROWS / 128, 4, 4), 256, 0, stream>>>(xb, Wq, Wk, Wv, bq, bk, bv,
                                                           Wpos, bpos, pospb, qb, kbuf, vtb);

    attn_mfma<<<dim3(B * H, T / QBLK), 512, 0, stream>>>(qb, kbuf, vtb, pospb, u_bias, v_bias, ctxb);

    outproj_mfma<<<dim3(M_ROWS / 64, 4), 256, 0, stream>>>(ctxb, Wo, bo, out);
}

// Round 19
// 40.593 us; speedup vs baseline: 1.0923x; 1.0923x over previous
//
#include <hip/hip_runtime.h>
#include <hip/hip_bf16.h>
#include <math.h>

#define B 16
#define T 512
#define D 256
#define H 4
#define HD 64
#define MAXREL 30
#define NREL 61
#define M_ROWS (B*T)     // 8192
#define QBLK 128

typedef __attribute__((ext_vector_type(8))) short bf16x8;
typedef __attribute__((ext_vector_type(4))) float f32x4;
typedef unsigned short ush;

__device__ inline ush f2b(float f) {
    __hip_bfloat16 h = __float2bfloat16(f);
    union { __hip_bfloat16 h; ush u; } c; c.h = h; return c.u;
}
__device__ inline float b2f(ush u) {
    union { ush u; __hip_bfloat16 h; } c; c.u = u; return __bfloat162float(c.h);
}
// pack two floats -> bf16 pair (low = a, high = b); lowers to v_cvt_pk_bf16_f32
__device__ inline unsigned int pk2(float a, float b) {
    __hip_bfloat162 h = __float22bfloat162_rn(make_float2(a, b));
    union { __hip_bfloat162 h; unsigned int u; } c; c.h = h; return c.u;
}
// swizzled byte offset inside a [rows][64] bf16 tile (128B rows)
__device__ inline int swz(int row, int byteoff) {
    return row * 128 + (byteoff ^ ((row & 7) << 4));
}
// swizzled byte offset inside a [rows][128] bf16 tile (256B rows)
__device__ inline int swz256(int row, int byteoff) {
    return row * 256 + (byteoff ^ ((row & 7) << 4));
}
// swizzled byte offset inside a [rows][256] bf16 tile (512B rows)
__device__ inline int swz512(int row, int byteoff) {
    return row * 512 + (byteoff ^ ((row & 7) << 4));
}

#define SCL 0.1803368801111204f   // 0.125 * log2(e)

// ---------------------------------------------------------------------------
// prep: LN (blocks 0..511, 16 rows each) + weight bf16 conv (512..767) +
// MFMA pos table (768..771, one block per head) -> pospb[h][rel][d] bf16.
// ---------------------------------------------------------------------------
__global__ __launch_bounds__(256) void prep_kernel(const float* __restrict__ x,
                                                   const float* __restrict__ gamma,
                                                   const float* __restrict__ beta,
                                                   ush* __restrict__ xb,
                                                   const float* __restrict__ Wq, const float* __restrict__ Wk,
                                                   const float* __restrict__ Wv, const float* __restrict__ Wo,
                                                   ush* __restrict__ wb,
                                                   const float* __restrict__ Wpos,
                                                   const float* __restrict__ bpos,
                                                   ush* __restrict__ pospb) {
    __shared__ __attribute__((aligned(16))) ush wpS[64 * 256];   // 32KB (pos blocks only)
    int bid = blockIdx.x;
    int tid = threadIdx.x;
    if (bid < 512) {
        int lane = tid & 63;
        float4 g = *(const float4*)(gamma + lane * 4);
        float4 bb = *(const float4*)(beta + lane * 4);
        #pragma unroll
        for (int it = 0; it < 4; ++it) {
            int row = bid * 16 + it * 4 + (tid >> 6);
            const float* xr = x + (size_t)row * D;
            float4 v = *(const float4*)(xr + lane * 4);
            float s = v.x + v.y + v.z + v.w;
            #pragma unroll
            for (int off = 32; off; off >>= 1) s += __shfl_xor(s, off);
            float mu = s * (1.f / 256.f);
            float dx = v.x - mu, dy = v.y - mu, dz = v.z - mu, dw = v.w - mu;
            float vs = dx*dx + dy*dy + dz*dz + dw*dw;
            #pragma unroll
            for (int off = 32; off; off >>= 1) vs += __shfl_xor(vs, off);
            float rstd = rsqrtf(vs * (1.f / 256.f) + 1e-5f);
            ushort4 o;
            o.x = f2b(dx * rstd * g.x + bb.x);
            o.y = f2b(dy * rstd * g.y + bb.y);
            o.z = f2b(dz * rstd * g.z + bb.z);
            o.w = f2b(dw * rstd * g.w + bb.w);
            *(ushort4*)(xb + (size_t)row * D + lane * 4) = o;
        }
    } else if (bid < 512 + 256) {
        int b2 = bid - 512;
        int z = b2 >> 6, xblk = b2 & 63;
        const float* src = z == 0 ? Wq : z == 1 ? Wk : z == 2 ? Wv : Wo;
        int idx = (xblk * 256 + tid) * 4;
        float4 v = *(const float4*)(src + idx);
        ushort4 o;
        o.x = f2b(v.x); o.y = f2b(v.y); o.z = f2b(v.z); o.w = f2b(v.w);
        *(ushort4*)(wb + (size_t)z * 65536 + idx) = o;
    } else {
        // ---- MFMA pos table for head h: posp_h = enc @ Wpos_h^T + bpos_h ----
        int h = bid - 768;
        int w = tid >> 6, l = tid & 63, lg = l >> 4, ln = l & 15;
        const float* wsrc = Wpos + (size_t)(h * 64) * D;
        #pragma unroll
        for (int c = 0; c < 16; ++c) {
            int idx = c * 256 + tid;
            int row = idx >> 6, col = (idx & 63) * 4;
            float4 v = *(const float4*)(wsrc + (size_t)row * D + col);
            ushort4 o; o.x = f2b(v.x); o.y = f2b(v.y); o.z = f2b(v.z); o.w = f2b(v.w);
            *(ushort4*)((char*)wpS + swz512(row, col * 2)) = o;
        }
        int p = w * 16 + ln;
        bf16x8 af[8];
        #pragma unroll
        for (int ks = 0; ks < 8; ++ks) {
            #pragma unroll
            for (int j = 0; j < 8; ++j) {
                int k = ks * 32 + lg * 8 + j;
                int i = k >> 1;
                float dt = __expf(-(2.f * i) * (9.210340371976184f / 256.f));
                float ang = (float)p * dt;
                float v = (k & 1) ? __cosf(ang) : __sinf(ang);
                af[ks][j] = (short)f2b(v);
            }
        }
        __syncthreads();
        f32x4 acc[4] = {};
        #pragma unroll
        for (int ks = 0; ks < 8; ++ks) {
            int kbyte = (ks * 32 + lg * 8) * 2;
            #pragma unroll
            for (int ct = 0; ct < 4; ++ct) {
                bf16x8 bf = *(const bf16x8*)((const char*)wpS + swz512(ct * 16 + ln, kbyte));
                acc[ct] = __builtin_amdgcn_mfma_f32_16x16x32_bf16(af[ks], bf, acc[ct], 0, 0, 0);
            }
        }
        #pragma unroll
        for (int ct = 0; ct < 4; ++ct) {
            int dcol = ct * 16 + ln;
            float bb = bpos[h * 64 + dcol];
            #pragma unroll
            for (int r = 0; r < 4; ++r) {
                int pr = w * 16 + lg * 4 + r;
                pospb[(size_t)h * 4096 + pr * 64 + dcol] = f2b(acc[ct][r] + bb);
            }
        }
    }
}

// ---------------------------------------------------------------------------
// Fused QKV projection, 128(tokens)x64(features) tiles, BK=128.
// grid (64, 4, 3), 48KB LDS -> 3 blocks/CU, zero tail imbalance.
// ---------------------------------------------------------------------------
__global__ __launch_bounds__(256, 3) void qkv_mfma(const ush* __restrict__ A,
                                                   const ush* __restrict__ wball,
                                                   const float* __restrict__ bq,
                                                   const float* __restrict__ bk,
                                                   const float* __restrict__ bv,
                                                   ush* __restrict__ qb,
                                                   ush* __restrict__ kbuf,
                                                   ush* __restrict__ vtb) {
    __shared__ __attribute__((aligned(16))) ush A_s[128 * 128];  // token tile
    __shared__ __attribute__((aligned(16))) ush B_s[64 * 128];   // W tile
    int tid = threadIdx.x;
    int w = tid >> 6, l = tid & 63;
    int lg = l >> 4, ln = l & 15;
    int wr = w >> 1, wc = w & 1;
    int i0 = blockIdx.x * 128;   // tokens
    int j0 = blockIdx.y * 64;    // features
    int z = blockIdx.z;
    const ush* Wp = wball + (size_t)z * 65536 + (size_t)j0 * D;
    const ush* Ap = A + (size_t)i0 * D;
    const float* bias = z == 0 ? bq : (z == 1 ? bk : bv);
    f32x4 acc[2][4] = {};

    #pragma unroll 1
    for (int kb2 = 0; kb2 < 2; ++kb2) {
        int k0 = kb2 * 128;
        if (kb2) __syncthreads();
        #pragma unroll
        for (int c = 0; c < 8; ++c) {
            int u = c * 256 + tid;
            int row = u >> 4, sub = u & 15;
            *(bf16x8*)((char*)A_s + swz256(row, sub * 16)) = *(const bf16x8*)(Ap + (size_t)row * D + k0 + sub * 8);
        }
        #pragma unroll
        for (int c = 0; c < 4; ++c) {
            int u = c * 256 + tid;
            int row = u >> 4, sub = u & 15;
            *(bf16x8*)((char*)B_s + swz256(row, sub * 16)) = *(const bf16x8*)(Wp + (size_t)row * D + k0 + sub * 8);
        }
        __syncthreads();
        __builtin_amdgcn_s_setprio(1);
        #pragma unroll
        for (int ksub = 0; ksub < 4; ++ksub) {
            int kbyte = ksub * 64 + lg * 16;
            bf16x8 af[2], bfr[4];
            #pragma unroll
            for (int mi = 0; mi < 2; ++mi)
                af[mi] = *(const bf16x8*)((const char*)B_s + swz256(wr * 32 + mi * 16 + ln, kbyte));
            #pragma unroll
            for (int ni = 0; ni < 4; ++ni)
                bfr[ni] = *(const bf16x8*)((const char*)A_s + swz256(wc * 64 + ni * 16 + ln, kbyte));
            #pragma unroll
            for (int mi = 0; mi < 2; ++mi)
                #pragma unroll
                for (int ni = 0; ni < 4; ++ni)
                    acc[mi][ni] = __builtin_amdgcn_mfma_f32_16x16x32_bf16(af[mi], bfr[ni], acc[mi][ni], 0, 0, 0);
        }
        __builtin_amdgcn_s_setprio(0);
    }

    if (z == 2) {
        // V^T: D[j][t], 4 consecutive j per quad -> scalar stores vtb[j][t]
        #pragma unroll
        for (int mi = 0; mi < 2; ++mi) {
            int jb = j0 + wr * 32 + mi * 16 + lg * 4;
            float4 bv4 = *(const float4*)(bias + jb);
            float bvv[4] = {bv4.x, bv4.y, bv4.z, bv4.w};
            #pragma unroll
            for (int ni = 0; ni < 4; ++ni) {
                int t = i0 + wc * 64 + ni * 16 + ln;
                #pragma unroll
                for (int r = 0; r < 4; ++r)
                    vtb[(size_t)(jb + r) * M_ROWS + t] = f2b(acc[mi][ni][r] + bvv[r]);
            }
        }
    } else {
        ush* ob = (z == 0) ? qb : kbuf;
        #pragma unroll
        for (int mi = 0; mi < 2; ++mi) {
            int jb = j0 + wr * 32 + mi * 16 + lg * 4;
            float4 bv4 = *(const float4*)(bias + jb);
            #pragma unroll
            for (int ni = 0; ni < 4; ++ni) {
                int t = i0 + wc * 64 + ni * 16 + ln;
                ushort4 o;
                o.x = f2b(acc[mi][ni][0] + bv4.x); o.y = f2b(acc[mi][ni][1] + bv4.y);
                o.z = f2b(acc[mi][ni][2] + bv4.z); o.w = f2b(acc[mi][ni][3] + bv4.w);
                *(ushort4*)(ob + (size_t)t * D + jb) = o;
            }
        }
    }
}

// ---------------------------------------------------------------------------
// Out-projection: 64x64 tiles, grid (128, 4) = 512 blocks = 2/CU exact.
// ---------------------------------------------------------------------------
__global__ __launch_bounds__(256, 2) void outproj_mfma(const ush* __restrict__ A,
                                                       const ush* __restrict__ W,
                                                       const float* __restrict__ bias,
                                                       float* __restrict__ of) {
    __shared__ __attribute__((aligned(16))) ush A_s[64 * 128];
    __shared__ __attribute__((aligned(16))) ush B_s[64 * 128];
    int tid = threadIdx.x;
    int w = tid >> 6, l = tid & 63;
    int lg = l >> 4, ln = l & 15;
    int wr = w >> 1, wc = w & 1;
    int i0 = blockIdx.x * 64;   // tokens
    int j0 = blockIdx.y * 64;   // features
    const ush* Ap = A + (size_t)i0 * D;
    const ush* Wp = W + (size_t)j0 * D;
    f32x4 acc[2][2] = {};

    #pragma unroll 1
    for (int kb2 = 0; kb2 < 2; ++kb2) {
        int k0 = kb2 * 128;
        if (kb2) __syncthreads();
        #pragma unroll
        for (int c = 0; c < 4; ++c) {
            int u = c * 256 + tid;
            int row = u >> 4, sub = u & 15;
            *(bf16x8*)((char*)A_s + swz256(row, sub * 16)) = *(const bf16x8*)(Ap + (size_t)row * D + k0 + sub * 8);
            *(bf16x8*)((char*)B_s + swz256(row, sub * 16)) = *(const bf16x8*)(Wp + (size_t)row * D + k0 + sub * 8);
        }
        __syncthreads();
        __builtin_amdgcn_s_setprio(1);
        #pragma unroll
        for (int ksub = 0; ksub < 4; ++ksub) {
            int kbyte = ksub * 64 + lg * 16;
            bf16x8 af[2], bfr[2];
            #pragma unroll
            for (int mi = 0; mi < 2; ++mi)
                af[mi] = *(const bf16x8*)((const char*)B_s + swz256(wr * 32 + mi * 16 + ln, kbyte));
            #pragma unroll
            for (int ni = 0; ni < 2; ++ni)
                bfr[ni] = *(const bf16x8*)((const char*)A_s + swz256(wc * 32 + ni * 16 + ln, kbyte));
            #pragma unroll
            for (int mi = 0; mi < 2; ++mi)
                #pragma unroll
                for (int ni = 0; ni < 2; ++ni)
                    acc[mi][ni] = __builtin_amdgcn_mfma_f32_16x16x32_bf16(af[mi], bfr[ni], acc[mi][ni], 0, 0, 0);
        }
        __builtin_amdgcn_s_setprio(0);
    }

    #pragma unroll
    for (int mi = 0; mi < 2; ++mi) {
        int jb = j0 + wr * 32 + mi * 16 + lg * 4;
        float4 bv4 = *(const float4*)(bias + jb);
        #pragma unroll
        for (int ni = 0; ni < 2; ++ni) {
            int t = i0 + wc * 32 + ni * 16 + ln;
            float4 o;
            o.x = acc[mi][ni][0] + bv4.x; o.y = acc[mi][ni][1] + bv4.y;
            o.z = acc[mi][ni][2] + bv4.z; o.w = acc[mi][ni][3] + bv4.w;
            *(float4*)(of + (size_t)t * D + jb) = o;
        }
    }
}

// ---------------------------------------------------------------------------
// Flash MFMA attention, TWO-TILE software pipeline: 4 K/V LDS buffers
// (2 ping-pong pairs), 2 KV tiles computed per barrier. Tile 2i+1's QK^T
// reads are independent of tile 2i's softmax/PV -> cross-tile ILP; barriers
// 10 -> 6. QBLK=128, 8 waves, swapped QK^T, cvt_pk P writes, static-max
// exp2 softmax, l-sum via ones-MFMA, scalar clipped-tile pd constants.
// ---------------------------------------------------------------------------
__global__ __launch_bounds__(512, 2) void attn_mfma(const ush* __restrict__ qb,
                                                    const ush* __restrict__ kb,
                                                    const ush* __restrict__ vtb,
                                                    const ush* __restrict__ pospb,
                                                    const float* __restrict__ u_bias,
                                                    const float* __restrict__ v_bias,
                                                    ush* __restrict__ ctxb) {
    __shared__ __attribute__((aligned(16))) ush Kd[4][64 * 64];   // 32KB: 2 ping-pong pairs (buf2 = posp in prologue)
    __shared__ __attribute__((aligned(16))) ush Vd[4][64 * 64];   // 32KB
    __shared__ __attribute__((aligned(16))) ush pdS[8][16 * 66];  // per-wave pd[q_loc][rel]
    __shared__ __attribute__((aligned(16))) ush PlS[8][16 * 64];  // per-wave P[q_loc][s] (swizzled)

    int tid = threadIdx.x;
    int w = tid >> 6;          // wave 0..7
    int l = tid & 63;
    int lg = l >> 4, ln = l & 15;
    int bh = blockIdx.x;
    int b = bh >> 2, h = bh & 3;
    int t0 = blockIdx.y * QBLK;
    const size_t baseBH = ((size_t)b * T) * D + h * HD;

    // ---- Q fragments in registers, pre-scaled by 0.125*log2(e) ----
    bf16x8 qu[2], qv[2];
    {
        const ush* qrow = qb + baseBH + (size_t)(t0 + w * 16 + ln) * D;
        int c0 = lg * 8;
        #pragma unroll
        for (int ks = 0; ks < 2; ++ks) {
            bf16x8 ld = *(const bf16x8*)(qrow + ks * 32 + c0);
            float4 ub0 = *(const float4*)(u_bias + h * HD + ks * 32 + c0);
            float4 ub1 = *(const float4*)(u_bias + h * HD + ks * 32 + c0 + 4);
            float4 vb0 = *(const float4*)(v_bias + h * HD + ks * 32 + c0);
            float4 vb1 = *(const float4*)(v_bias + h * HD + ks * 32 + c0 + 4);
            float ubv[8] = {ub0.x,ub0.y,ub0.z,ub0.w,ub1.x,ub1.y,ub1.z,ub1.w};
            float vbv[8] = {vb0.x,vb0.y,vb0.z,vb0.w,vb1.x,vb1.y,vb1.z,vb1.w};
            #pragma unroll
            for (int j = 0; j < 8; ++j) {
                float f = b2f((ush)ld[j]);
                qu[ks][j] = (short)f2b((f + ubv[j]) * SCL);
                qv[ks][j] = (short)f2b((f + vbv[j]) * SCL);
            }
        }
    }

    // staging chunk index: each of 512 threads owns ONE 16B chunk of a 64x64 tile
    int r0 = tid >> 3, c0 = tid & 7;
    const ush* kbase = kb + baseBH;
    const ush* vbase = vtb + (size_t)(h * HD) * M_ROWS + (size_t)b * T;
    const ush* pbase = pospb + (size_t)h * 4096;

    // ---- prologue: stage posp->Kd[2], tiles 0,1 -> pair {0,1}; prefetch 2,3 ----
    {
        bf16x8 pp0 = *(const bf16x8*)(pbase + r0 * 64 + c0 * 8);
        bf16x8 k0 = *(const bf16x8*)(kbase + (size_t)r0 * D + c0 * 8);
        bf16x8 k1 = *(const bf16x8*)(kbase + (size_t)(64 + r0) * D + c0 * 8);
        bf16x8 v0 = *(const bf16x8*)(vbase + (size_t)r0 * M_ROWS + c0 * 8);
        bf16x8 v1 = *(const bf16x8*)(vbase + (size_t)r0 * M_ROWS + 64 + c0 * 8);
        *(bf16x8*)((char*)Kd[2] + swz(r0, c0 * 16)) = pp0;
        *(bf16x8*)((char*)Kd[0] + swz(r0, c0 * 16)) = k0;
        *(bf16x8*)((char*)Kd[1] + swz(r0, c0 * 16)) = k1;
        *(bf16x8*)((char*)Vd[0] + swz(r0, c0 * 16)) = v0;
        *(bf16x8*)((char*)Vd[1] + swz(r0, c0 * 16)) = v1;
    }
    bf16x8 sk0 = *(const bf16x8*)(kbase + (size_t)(128 + r0) * D + c0 * 8);
    bf16x8 sk1 = *(const bf16x8*)(kbase + (size_t)(192 + r0) * D + c0 * 8);
    bf16x8 sv0 = *(const bf16x8*)(vbase + (size_t)r0 * M_ROWS + 128 + c0 * 8);
    bf16x8 sv1 = *(const bf16x8*)(vbase + (size_t)r0 * M_ROWS + 192 + c0 * 8);
    __syncthreads();

    // ---- pd[q_loc][rel] via MFMA from Kd[2] (posp), log2-scaled via qv ----
    ush* pdW = pdS[w];
    {
        f32x4 pacc[4] = {};
        #pragma unroll
        for (int ks = 0; ks < 2; ++ks)
            #pragma unroll
            for (int ct = 0; ct < 4; ++ct) {
                bf16x8 bf = *(const bf16x8*)((const char*)Kd[2] + swz(ct * 16 + ln, (ks * 32 + lg * 8) * 2));
                pacc[ct] = __builtin_amdgcn_mfma_f32_16x16x32_bf16(qv[ks], bf, pacc[ct], 0, 0, 0);
            }
        // cols 61..63 pad, never gathered (|rel|<=30)
        #pragma unroll
        for (int ct = 0; ct < 4; ++ct)
            #pragma unroll
            for (int r = 0; r < 4; ++r)
                pdW[(lg * 4 + r) * 66 + ct * 16 + ln] = f2b(pacc[ct][r]);
    }
    // per-lane scalar constants for fully-clipped tiles (lane's q_loc = ln)
    float pdlo = b2f(pdW[ln * 66 + 0]);
    float pdhi = b2f(pdW[ln * 66 + 60]);
    __syncthreads();   // all waves done reading Kd[2] before iter0 commit targets it

    // ---- main loop: 4 iterations, 2 KV tiles per barrier ----
    f32x4 lacc = {};
    f32x4 o_acc[4] = {};
    ush* pw = PlS[w];
    bf16x8 ones;
    #pragma unroll
    for (int j = 0; j < 8; ++j) ones[j] = (short)0x3F80;   // bf16 1.0

    #pragma unroll 1
    for (int it = 0; it < 4; ++it) {
        int cb = (it & 1) * 2;   // current pair base {cb, cb+1}
        int ob = cb ^ 2;         // other pair base (commit target)
        // commit tiles 2it+2, 2it+3 (readers of pair ob finished before last barrier)
        if (it < 3) {
            *(bf16x8*)((char*)Kd[ob] + swz(r0, c0 * 16)) = sk0;
            *(bf16x8*)((char*)Kd[ob + 1] + swz(r0, c0 * 16)) = sk1;
            *(bf16x8*)((char*)Vd[ob] + swz(r0, c0 * 16)) = sv0;
            *(bf16x8*)((char*)Vd[ob + 1] + swz(r0, c0 * 16)) = sv1;
        }
        // issue loads for tiles 2it+4, 2it+5
        if (it < 2) {
            int sn = it * 128 + 256;
            sk0 = *(const bf16x8*)(kbase + (size_t)(sn + r0) * D + c0 * 8);
            sk1 = *(const bf16x8*)(kbase + (size_t)(sn + 64 + r0) * D + c0 * 8);
            sv0 = *(const bf16x8*)(vbase + (size_t)r0 * M_ROWS + sn + c0 * 8);
            sv1 = *(const bf16x8*)(vbase + (size_t)r0 * M_ROWS + sn + 64 + c0 * 8);
        }

        // ---- two tiles back-to-back (tt=1's QK^T independent of tt=0's PV) ----
        #pragma unroll
        for (int tt = 0; tt < 2; ++tt) {
            int s0 = (2 * it + tt) * 64;
            const char* Kc = (const char*)Kd[cb + tt];
            const char* Vc = (const char*)Vd[cb + tt];

            // sacc init: per-lane scalar pd for fully-clipped tiles
            // all rel >= 30 <=> dlt >= 192; all rel <= -30 <=> dlt <= -128
            int dlt = s0 - t0;
            float cinit;
            if (dlt >= 192) cinit = pdhi;
            else if (dlt <= -128) cinit = pdlo;
            else cinit = 0.f;
            f32x4 sacc[4];
            #pragma unroll
            for (int ct = 0; ct < 4; ++ct)
                #pragma unroll
                for (int r = 0; r < 4; ++r) sacc[ct][r] = cinit;

            // SWAPPED QK^T: D = S^T, lane holds s = ct*16 + lg*4 + r, q = w*16 + ln
            __builtin_amdgcn_s_setprio(1);
            #pragma unroll
            for (int ks = 0; ks < 2; ++ks)
                #pragma unroll
                for (int ct = 0; ct < 4; ++ct) {
                    bf16x8 kf = *(const bf16x8*)(Kc + swz(ct * 16 + ln, (ks * 32 + lg * 8) * 2));
                    sacc[ct] = __builtin_amdgcn_mfma_f32_16x16x32_bf16(kf, qu[ks], sacc[ct], 0, 0, 0);
                }
            __builtin_amdgcn_s_setprio(0);

            // partially-clipped tiles: gather pd from LDS (q_loc = ln per lane)
            if (dlt > -128 && dlt < 192) {
                int t_glob = t0 + w * 16 + ln;
                #pragma unroll
                for (int ct = 0; ct < 4; ++ct) {
                    #pragma unroll
                    for (int r = 0; r < 4; ++r) {
                        int s_g = s0 + ct * 16 + lg * 4 + r;
                        int rel = s_g - t_glob;
                        rel = rel < -MAXREL ? -MAXREL : (rel > MAXREL ? MAXREL : rel);
                        sacc[ct][r] += b2f(pdW[ln * 66 + rel + MAXREL]);
                    }
                }
            }

            // static-max softmax: P = exp2(s) directly
            #pragma unroll
            for (int ct = 0; ct < 4; ++ct)
                #pragma unroll
                for (int r = 0; r < 4; ++r)
                    sacc[ct][r] = exp2f(sacc[ct][r]);

            // P -> per-wave LDS, packed pairs (s-adjacent): 8 x b32 writes
            #pragma unroll
            for (int ct = 0; ct < 4; ++ct)
                #pragma unroll
                for (int rr = 0; rr < 2; ++rr)
                    *(unsigned int*)((char*)pw + swz(ln, (ct * 16 + lg * 4 + rr * 2) * 2)) =
                        pk2(sacc[ct][rr * 2], sacc[ct][rr * 2 + 1]);

            // PV + l-sum via ones-MFMA (A-frag reads P[q=ln][s-chunk])
            __builtin_amdgcn_s_setprio(1);
            #pragma unroll
            for (int ks = 0; ks < 2; ++ks) {
                bf16x8 pa = *(const bf16x8*)((const char*)pw + swz(ln, (ks * 32 + lg * 8) * 2));
                #pragma unroll
                for (int cd = 0; cd < 4; ++cd) {
                    bf16x8 bv8 = *(const bf16x8*)(Vc + swz(cd * 16 + ln, (ks * 32 + lg * 8) * 2));
                    o_acc[cd] = __builtin_amdgcn_mfma_f32_16x16x32_bf16(pa, bv8, o_acc[cd], 0, 0, 0);
                }
                lacc = __builtin_amdgcn_mfma_f32_16x16x32_bf16(pa, ones, lacc, 0, 0, 0);
            }
            __builtin_amdgcn_s_setprio(0);
        }

        __syncthreads();   // single barrier per 2 tiles
    }

    // ---- normalize + write ctx (bf16 row-major) ----
    float inv[4];
    #pragma unroll
    for (int r = 0; r < 4; ++r) inv[r] = 1.f / lacc[r];
    #pragma unroll
    for (int cd = 0; cd < 4; ++cd)
        #pragma unroll
        for (int r = 0; r < 4; ++r) {
            int t_loc = w * 16 + lg * 4 + r;
            ctxb[baseBH + (size_t)(t0 + t_loc) * D + cd * 16 + ln] = f2b(o_acc[cd][r] * inv[r]);
        }
}

// ---------------------------------------------------------------------------
extern "C" void kernel_launch(void* const* d_in, const int* in_sizes, int n_in,
                              void* d_out, int out_size, void* d_ws, size_t ws_size,
                              hipStream_t stream) {
    const float* inputs  = (const float*)d_in[0];
    const float* ln_g    = (const float*)d_in[1];
    const float* ln_b    = (const float*)d_in[2];
    const float* Wq      = (const float*)d_in[3];
    const float* bq      = (const float*)d_in[4];
    const float* Wk      = (const float*)d_in[5];
    const float* bk      = (const float*)d_in[6];
    const float* Wv      = (const float*)d_in[7];
    const float* bv      = (const float*)d_in[8];
    const float* Wpos    = (const float*)d_in[9];
    const float* bpos    = (const float*)d_in[10];
    const float* Wo      = (const float*)d_in[11];
    const float* bo      = (const float*)d_in[12];
    const float* u_bias  = (const float*)d_in[13];
    const float* v_bias  = (const float*)d_in[14];
    float* out = (float*)d_out;

    char* w = (char*)d_ws;
    ush* xb    = (ush*)w;  w += (size_t)M_ROWS * D * 2;   // 4MB
    ush* qb    = (ush*)w;  w += (size_t)M_ROWS * D * 2;
    ush* kbuf  = (ush*)w;  w += (size_t)M_ROWS * D * 2;
    ush* vtb   = (ush*)w;  w += (size_t)M_ROWS * D * 2;
    ush* ctxb  = (ush*)w;  w += (size_t)M_ROWS * D * 2;
    ush* wb    = (ush*)w;  w += (size_t)4 * 65536 * 2;    // 512KB
    ush* pospb = (ush*)w;  w += (size_t)4 * 64 * 64 * 2;  // 32KB

    prep_kernel<<<512 + 256 + 4, 256, 0, stream>>>(inputs, ln_g, ln_b, xb,
                                                   Wq, Wk, Wv, Wo, wb,
                                                   Wpos, bpos, pospb);

    qkv_mfma<<<dim3(M_ROWS / 128, 4, 3), 256, 0, stream>>>(xb, wb, bq, bk, bv, qb, kbuf, vtb);

    attn_mfma<<<dim3(B * H, T / QBLK), 512, 0, stream>>>(qb, kbuf, vtb, pospb, u_bias, v_bias, ctxb);

    outproj_mfma<<<dim3(M_ROWS / 64, 4), 256, 0, stream>>>(ctxb, wb + 3 * 65536, bo, out);
}